// Round 17
// baseline (286.327 us; speedup 1.0000x reference)
//
#include <hip/hip_runtime.h>
#include <hip/hip_bf16.h>
#include <stdint.h>
#include <string.h>

#define NN 50000
#define NE 800000
#define SCAN_B 200
#define SCAN_CH 250

typedef short bf8_t __attribute__((ext_vector_type(8)));
typedef float f32x4 __attribute__((ext_vector_type(4)));

__device__ __forceinline__ float silu_f(float v) {
    return v * __builtin_amdgcn_rcpf(1.0f + __expf(-v));
}

__device__ __forceinline__ unsigned int pack2bf(float a, float b) {
    __hip_bfloat162 h = __float22bfloat162_rn(make_float2(a, b));
    unsigned int u; memcpy(&u, &h, 4);
    return u;
}

__device__ __forceinline__ float bf_lo(unsigned int u) { return __uint_as_float(u << 16); }
__device__ __forceinline__ float bf_hi(unsigned int u) { return __uint_as_float(u & 0xffff0000u); }

union U4B { uint4 u; bf8_t b; };
__device__ __forceinline__ bf8_t as_bf8(uint4 u) { U4B x; x.u = u; return x.b; }

// ---------------------------------------------------------------------------
// prep_w: weight fragments in MFMA A-operand order (W^T), bf16.
// ---------------------------------------------------------------------------
__global__ __launch_bounds__(64) void prep_w(const float* __restrict__ We1,
                                             const float* __restrict__ We2,
                                             const float* __restrict__ Wn1,
                                             const float* __restrict__ Wn2,
                                             unsigned short* __restrict__ wf1,
                                             unsigned short* __restrict__ wf2,
                                             unsigned short* __restrict__ wfn1,
                                             unsigned short* __restrict__ wfn2) {
    int b = blockIdx.x, lane = threadIdx.x;
    int q = lane >> 4, c = lane & 15;
    const float* W; unsigned short* dst; int f;
    if (b < 64)       { W = We1; f = b;       dst = wf1  + (size_t)f * 512; }
    else if (b < 96)  { W = We2; f = b - 64;  dst = wf2  + (size_t)f * 512; }
    else if (b < 160) { W = Wn1; f = b - 96;  dst = wfn1 + (size_t)f * 512; }
    else              { W = Wn2; f = b - 160; dst = wfn2 + (size_t)f * 512; }
    int s = f >> 3, mf = f & 7;
    int k0 = s * 32 + q * 8, col = mf * 16 + c;
    float v[8];
    #pragma unroll
    for (int i = 0; i < 8; ++i) v[i] = W[(size_t)(k0 + i) * 128 + col];
    uint4 o;
    o.x = pack2bf(v[0], v[1]); o.y = pack2bf(v[2], v[3]);
    o.z = pack2bf(v[4], v[5]); o.w = pack2bf(v[6], v[7]);
    *(uint4*)(dst + lane * 8) = o;
}

// ---------------------------------------------------------------------------
// prep_node: fused (a) edge-row histogram, (b) THREE GEMMs sharing one pass
// over x: z = x@We1_top + be1, y = x@We1_mid, zn = x@Wn1_top + bn1.
// ---------------------------------------------------------------------------
__global__ __launch_bounds__(256, 2) void prep_node(
    const float* __restrict__ x, const int* __restrict__ ei,
    const unsigned short* __restrict__ wf1, const unsigned short* __restrict__ wfn1,
    const float* __restrict__ be1, const float* __restrict__ bn1,
    unsigned short* __restrict__ zbf, unsigned short* __restrict__ ybf,
    unsigned short* __restrict__ znbf, int* __restrict__ cnt)
{
    const int tid = threadIdx.x;
    const int n0 = blockIdx.x * 64;
    const char* w1 = (const char*)wf1;
    const char* wn = (const char*)wfn1;

    {
        int e0 = (blockIdx.x * 256 + tid) * 4;
        if (e0 < NE) {
            int4 r4 = *(const int4*)(ei + e0);
            atomicAdd(&cnt[r4.x], 1); atomicAdd(&cnt[r4.y], 1);
            atomicAdd(&cnt[r4.z], 1); atomicAdd(&cnt[r4.w], 1);
        }
    }

    const int P = tid >> 6, lane = tid & 63;
    const int q = lane >> 4, e16 = lane & 15;
    const int oc_q = P * 32 + q * 4;

    int nloc[4]; unsigned nb[4];
    #pragma unroll
    for (int t = 0; t < 4; ++t) {
        int nl = t * 16 + e16; nloc[t] = nl;
        int node = n0 + nl; if (node >= NN) node = NN - 1;
        nb[t] = (unsigned)node;
    }

    f32x4 az[2][4], ay[2][4], an[2][4];
    #pragma unroll
    for (int M = 0; M < 2; ++M) {
        float4 b1 = *(const float4*)(be1 + oc_q + M * 16);
        float4 b2 = *(const float4*)(bn1 + oc_q + M * 16);
        #pragma unroll
        for (int t = 0; t < 4; ++t) {
            az[M][t][0] = b1.x; az[M][t][1] = b1.y; az[M][t][2] = b1.z; az[M][t][3] = b1.w;
            ay[M][t][0] = 0.f;  ay[M][t][1] = 0.f;  ay[M][t][2] = 0.f;  ay[M][t][3] = 0.f;
            an[M][t][0] = b2.x; an[M][t][1] = b2.y; an[M][t][2] = b2.z; an[M][t][3] = b2.w;
        }
    }

    #pragma unroll
    for (int s = 0; s < 4; ++s) {
        bf8_t bfr[4];
        #pragma unroll
        for (int t = 0; t < 4; ++t) {
            const float* src = x + ((size_t)nb[t]) * 128 + s * 32 + q * 8;
            float4 v0 = *(const float4*)src;
            float4 v1 = *(const float4*)(src + 4);
            uint4 o;
            o.x = pack2bf(v0.x, v0.y); o.y = pack2bf(v0.z, v0.w);
            o.z = pack2bf(v1.x, v1.y); o.w = pack2bf(v1.z, v1.w);
            bfr[t] = as_bf8(o);
        }
        #pragma unroll
        for (int M = 0; M < 2; ++M) {
            unsigned wz = ((unsigned)(s * 8 + P * 2 + M) << 10) + ((unsigned)lane << 4);
            unsigned wy = ((unsigned)((s + 4) * 8 + P * 2 + M) << 10) + ((unsigned)lane << 4);
            bf8_t afz = as_bf8(*(const uint4*)(w1 + wz));
            bf8_t afy = as_bf8(*(const uint4*)(w1 + wy));
            bf8_t afn = as_bf8(*(const uint4*)(wn + wz));
            #pragma unroll
            for (int t = 0; t < 4; ++t) {
                az[M][t] = __builtin_amdgcn_mfma_f32_16x16x32_bf16(afz, bfr[t], az[M][t], 0, 0, 0);
                ay[M][t] = __builtin_amdgcn_mfma_f32_16x16x32_bf16(afy, bfr[t], ay[M][t], 0, 0, 0);
                an[M][t] = __builtin_amdgcn_mfma_f32_16x16x32_bf16(afn, bfr[t], an[M][t], 0, 0, 0);
            }
        }
    }

    #pragma unroll
    for (int M = 0; M < 2; ++M) {
        #pragma unroll
        for (int t = 0; t < 4; ++t) {
            int node = n0 + nloc[t];
            if (node < NN) {
                uint2 pz, py, pn;
                pz.x = pack2bf(az[M][t][0], az[M][t][1]); pz.y = pack2bf(az[M][t][2], az[M][t][3]);
                py.x = pack2bf(ay[M][t][0], ay[M][t][1]); py.y = pack2bf(ay[M][t][2], ay[M][t][3]);
                pn.x = pack2bf(an[M][t][0], an[M][t][1]); pn.y = pack2bf(an[M][t][2], an[M][t][3]);
                *(uint2*)(zbf  + ((size_t)node << 7) + oc_q + M * 16) = pz;
                *(uint2*)(ybf  + ((size_t)node << 7) + oc_q + M * 16) = py;
                *(uint2*)(znbf + ((size_t)node << 7) + oc_q + M * 16) = pn;
            }
        }
    }
}

// ---------------------------------------------------------------------------
// Parallel CSR scan
// ---------------------------------------------------------------------------
__global__ __launch_bounds__(256) void scan_bsum(const int* __restrict__ cnt,
                                                 int* __restrict__ bsum) {
    __shared__ int red[4];
    int b = blockIdx.x, tid = threadIdx.x;
    int n = b * SCAN_CH + tid;
    int v = (tid < SCAN_CH) ? cnt[n] : 0;
    #pragma unroll
    for (int o = 32; o; o >>= 1) v += __shfl_down(v, o);
    if ((tid & 63) == 0) red[tid >> 6] = v;
    __syncthreads();
    if (tid == 0) bsum[b] = red[0] + red[1] + red[2] + red[3];
}

__global__ __launch_bounds__(256) void scan_write(const int* __restrict__ cnt,
                                                  const int* __restrict__ bsum,
                                                  int* __restrict__ off,
                                                  int* __restrict__ cur) {
    __shared__ int part[256];
    __shared__ int basered[4];
    int b = blockIdx.x, tid = threadIdx.x;
    int bv = (tid < b) ? bsum[tid] : 0;
    #pragma unroll
    for (int o = 32; o; o >>= 1) bv += __shfl_down(bv, o);
    if ((tid & 63) == 0) basered[tid >> 6] = bv;
    __syncthreads();
    int base = basered[0] + basered[1] + basered[2] + basered[3];
    int n = b * SCAN_CH + tid;
    int c = (tid < SCAN_CH) ? cnt[n] : 0;
    part[tid] = c;
    __syncthreads();
    #pragma unroll
    for (int d = 1; d < 256; d <<= 1) {
        int v = (tid >= d) ? part[tid - d] : 0;
        __syncthreads();
        part[tid] += v;
        __syncthreads();
    }
    if (tid < SCAN_CH) {
        int excl = base + part[tid] - c;
        off[n] = excl; cur[n] = excl;
    }
    if (b == SCAN_B - 1 && tid == SCAN_CH) off[NN] = NE;
}

// scatter: 4 edges/thread; computes dij and stores int4{row, col, dij, 0}
__global__ __launch_bounds__(256) void egnn_scatter(const int* __restrict__ ei,
                                                    const float* __restrict__ pos,
                                                    int* __restrict__ cur,
                                                    int4* __restrict__ rc_slot) {
    int e = (blockIdx.x * 256 + threadIdx.x) * 4;
    if (e < NE) {
        int4 r4 = *(const int4*)(ei + e);
        int4 c4 = *(const int4*)(ei + NE + e);
        #pragma unroll
        for (int j = 0; j < 4; ++j) {
            int r = (j == 0) ? r4.x : (j == 1) ? r4.y : (j == 2) ? r4.z : r4.w;
            int c = (j == 0) ? c4.x : (j == 1) ? c4.y : (j == 2) ? c4.z : c4.w;
            float dx = pos[r * 3 + 0] - pos[c * 3 + 0];
            float dy = pos[r * 3 + 1] - pos[c * 3 + 1];
            float dz = pos[r * 3 + 2] - pos[c * 3 + 2];
            float d = dx * dx + dy * dy + dz * dz;
            int p = atomicAdd(&cur[r], 1);
            rc_slot[p] = make_int4(r, c, __float_as_int(d), 0);
        }
    }
}

// ---------------------------------------------------------------------------
// Edge kernel. Block = 64 CSR slots, 256 threads = 4 waves, 3 barriers.
// 6 waves/SIMD requested; no setprio (lockstep-wave regime, m190).
// ---------------------------------------------------------------------------
__global__ __launch_bounds__(256, 6) void egnn_edge_mfma(
    const unsigned short* __restrict__ zbf, const unsigned short* __restrict__ ybf,
    const float* __restrict__ pos,
    const unsigned short* __restrict__ wf2,
    const float* __restrict__ We1,
    const float* __restrict__ be2, const float* __restrict__ Wc,
    const float* __restrict__ bc,
    const int4* __restrict__ rc_slot,
    float* __restrict__ agg, float* __restrict__ delta)
{
    __shared__ __align__(16) unsigned short HsBuf[9216];  // h1 (stride 136) / mT (stride 72)
    unsigned short* Hs = HsBuf;
    unsigned short* mT = HsBuf;
    __shared__ float rij_s[64][3];
    __shared__ float wdot[64];
    __shared__ int   seg_node[64], seg_start[65];
    __shared__ unsigned long long smask;
    __shared__ int firstPartial, lastPartial;

    const int tid = threadIdx.x;
    const int bid = blockIdx.x;
    const int xcd = bid & 7, ii = bid >> 3;
    const int blk = (xcd < 4 ? xcd * 1563 : 4 * 1563 + (xcd - 4) * 1562) + ii;
    const int e0 = blk * 64;
    const char* zb = (const char*)zbf;
    const char* yb = (const char*)ybf;
    const char* w2 = (const char*)wf2;

    const int P = tid >> 6, lane = tid & 63;
    const int q = lane >> 4, e16 = lane & 15;
    const int oc_q = P * 32 + q * 4;

    // per-thread slot records
    int eloc[4]; unsigned rb[4], cb[4]; float dijt[4];
    #pragma unroll
    for (int t = 0; t < 4; ++t) {
        int el = t * 16 + e16; eloc[t] = el;
        int4 sl = rc_slot[e0 + el];
        rb[t] = (unsigned)sl.x << 8;
        cb[t] = (unsigned)sl.y << 8;
        dijt[t] = __int_as_float(sl.z);
    }

    // hoisted z/y gathers
    uint2 uzr[2][4], uyr[2][4];
    #pragma unroll
    for (int M = 0; M < 2; ++M) {
        const unsigned cbyte = (unsigned)((oc_q + M * 16) << 1);
        #pragma unroll
        for (int t = 0; t < 4; ++t) {
            uzr[M][t] = *(const uint2*)(zb + rb[t] + cbyte);
            uyr[M][t] = *(const uint2*)(yb + cb[t] + cbyte);
        }
    }

    // wave 0: staging + segment detection, concurrent with other waves' L1
    if (tid < 64) {
        int4 sl = rc_slot[e0 + tid];
        int r = sl.x;
        #pragma unroll
        for (int k = 0; k < 3; ++k)
            rij_s[tid][k] = pos[r * 3 + k] - pos[sl.y * 3 + k];
        wdot[tid] = 0.f;
        seg_start[tid] = 64;
        if (tid == 0) seg_start[64] = 64;
        int prev = __shfl_up(r, 1);
        bool flag = (tid == 0) || (r != prev);
        unsigned long long b = __ballot(flag);
        int seg = __popcll(b & ((2ull << tid) - 1)) - 1;
        if (flag) { seg_node[seg] = r; seg_start[seg] = tid; }
        int r63 = __shfl(r, 63);
        if (tid == 0) {
            smask = b;
            firstPartial = (e0 > 0) && (rc_slot[e0 - 1].x == r);
            lastPartial  = (e0 + 64 < NE) && (rc_slot[e0 + 64].x == r63);
        }
    }

    // ---- layer 1: h1 = silu(z[row] + y[col] + dij*w256) ----
    #pragma unroll
    for (int M = 0; M < 2; ++M) {
        float4 w256 = *(const float4*)(We1 + (size_t)256 * 128 + oc_q + M * 16);
        #pragma unroll
        for (int t = 0; t < 4; ++t) {
            uint2 uz = uzr[M][t], uy = uyr[M][t];
            float d = dijt[t];
            float v0 = silu_f(bf_lo(uz.x) + bf_lo(uy.x) + d * w256.x);
            float v1 = silu_f(bf_hi(uz.x) + bf_hi(uy.x) + d * w256.y);
            float v2 = silu_f(bf_lo(uz.y) + bf_lo(uy.y) + d * w256.z);
            float v3 = silu_f(bf_hi(uz.y) + bf_hi(uy.y) + d * w256.w);
            uint2 pk; pk.x = pack2bf(v0, v1); pk.y = pack2bf(v2, v3);
            *(uint2*)(Hs + eloc[t] * 136 + oc_q + M * 16) = pk;
        }
    }
    __syncthreads();   // barrier 1

    // ---- layer 2: K=128 MFMA ----
    f32x4 acc2[2][4];
    #pragma unroll
    for (int M = 0; M < 2; ++M) {
        float4 bi = *(const float4*)(be2 + oc_q + M * 16);
        #pragma unroll
        for (int t = 0; t < 4; ++t) { acc2[M][t][0] = bi.x; acc2[M][t][1] = bi.y; acc2[M][t][2] = bi.z; acc2[M][t][3] = bi.w; }
    }

    #pragma unroll
    for (int s = 0; s < 4; ++s) {
        bf8_t bfr[4];
        #pragma unroll
        for (int t = 0; t < 4; ++t)
            bfr[t] = as_bf8(*(const uint4*)(Hs + eloc[t] * 136 + s * 32 + q * 8));
        #pragma unroll
        for (int M = 0; M < 2; ++M) {
            unsigned woff = ((unsigned)(s * 8 + P * 2 + M) << 10) + ((unsigned)lane << 4);
            bf8_t af = as_bf8(*(const uint4*)(w2 + woff));
            #pragma unroll
            for (int t = 0; t < 4; ++t)
                acc2[M][t] = __builtin_amdgcn_mfma_f32_16x16x32_bf16(af, bfr[t], acc2[M][t], 0, 0, 0);
        }
    }
    __syncthreads();   // barrier 2

    // ---- Phase A: m = silu(.) -> mT (transposed); wdot partials ----
    {
        float4 wcA = *(const float4*)(Wc + oc_q);
        float4 wcB = *(const float4*)(Wc + oc_q + 16);
        float part[4];
        #pragma unroll
        for (int t = 0; t < 4; ++t) part[t] = 0.f;

        #pragma unroll
        for (int M = 0; M < 2; ++M) {
            float4 wc = (M == 0) ? wcA : wcB;
            int cbase = oc_q + M * 16;
            #pragma unroll
            for (int t = 0; t < 4; ++t) {
                float v0 = silu_f(acc2[M][t][0]);
                float v1 = silu_f(acc2[M][t][1]);
                float v2 = silu_f(acc2[M][t][2]);
                float v3 = silu_f(acc2[M][t][3]);
                part[t] += v0 * wc.x + v1 * wc.y + v2 * wc.z + v3 * wc.w;
                unsigned ua = pack2bf(v0, v1), ub = pack2bf(v2, v3);
                int slot = eloc[t];
                mT[(cbase + 0) * 72 + slot] = (unsigned short)ua;
                mT[(cbase + 1) * 72 + slot] = (unsigned short)(ua >> 16);
                mT[(cbase + 2) * 72 + slot] = (unsigned short)ub;
                mT[(cbase + 3) * 72 + slot] = (unsigned short)(ub >> 16);
            }
        }
        #pragma unroll
        for (int t = 0; t < 4; ++t) {
            float p = part[t];
            p += __shfl_xor(p, 16);
            p += __shfl_xor(p, 32);
            if (q == 0) atomicAdd(&wdot[eloc[t]], p);
        }
    }
    __syncthreads();   // barrier 3

    // ---- Phase C: segment-sum ----
    {
        const int wv = tid >> 6, l = tid & 63;
        const int cA = l & 15, kq = l >> 4;
        const int nseg = __popcll(smask);

        if (nseg <= 16) {
            // fast path: selector-MFMA; wave handles 2 col-quadrants
            const int st = seg_start[cA];
            const int en = seg_start[cA + 1];
            f32x4 accd[2];
            #pragma unroll
            for (int c2 = 0; c2 < 2; ++c2) { accd[c2][0] = 0.f; accd[c2][1] = 0.f; accd[c2][2] = 0.f; accd[c2][3] = 0.f; }
            #pragma unroll
            for (int kt = 0; kt < 2; ++kt) {
                bf8_t aS;
                #pragma unroll
                for (int i = 0; i < 8; ++i) {
                    int k = kt * 32 + kq * 8 + i;
                    aS[i] = (k >= st && k < en) ? (short)0x3F80 : (short)0;
                }
                #pragma unroll
                for (int c2 = 0; c2 < 2; ++c2) {
                    int ct = wv * 2 + c2;
                    bf8_t bM = as_bf8(*(const uint4*)(mT + (ct * 16 + cA) * 72 + kt * 32 + kq * 8));
                    accd[c2] = __builtin_amdgcn_mfma_f32_16x16x32_bf16(aS, bM, accd[c2], 0, 0, 0);
                }
            }
            #pragma unroll
            for (int c2 = 0; c2 < 2; ++c2) {
                int ct = wv * 2 + c2;
                #pragma unroll
                for (int r = 0; r < 4; ++r) {
                    int sg = kq * 4 + r;
                    if (sg < nseg) {
                        float v = accd[c2][r];
                        int node = seg_node[sg];
                        bool partial = (sg == 0 && firstPartial) || (sg == nseg - 1 && lastPartial);
                        float* dst = agg + (size_t)node * 128 + ct * 16 + cA;
                        if (partial) atomicAdd(dst, v); else *dst = v;
                    }
                }
            }
        } else {
            // rare general path: SCALAR segment sums (few registers)
            const int c = tid & 127, g = tid >> 7;   // 128 cols x 2 seg groups
            for (int k = g; k < nseg; k += 2) {
                int st = seg_start[k];
                int en = seg_start[k + 1];
                float a = 0.f;
                for (int s2 = st; s2 < en; ++s2)
                    a += __uint_as_float((unsigned)mT[c * 72 + s2] << 16);
                int node = seg_node[k];
                bool partial = (k == 0 && firstPartial) || (k == nseg - 1 && lastPartial);
                float* dst = agg + (size_t)node * 128 + c;
                if (partial) atomicAdd(dst, a); else *dst = a;
            }
        }

        // delta tail
        if (tid < nseg) {
            float bcv = bc[0];
            int start = seg_start[tid];
            int end = (tid + 1 < nseg) ? seg_start[tid + 1] : 64;
            float d0 = 0.f, d1 = 0.f, d2 = 0.f;
            for (int s2 = start; s2 < end; ++s2) {
                float wgt = silu_f(wdot[s2] + bcv);
                d0 += rij_s[s2][0] * wgt;
                d1 += rij_s[s2][1] * wgt;
                d2 += rij_s[s2][2] * wgt;
            }
            int node = seg_node[tid];
            bool partial = (tid == 0 && firstPartial) || (tid == nseg - 1 && lastPartial);
            float* dd = delta + (size_t)node * 3;
            if (partial) { atomicAdd(dd, d0); atomicAdd(dd + 1, d1); atomicAdd(dd + 2, d2); }
            else         { dd[0] = d0; dd[1] = d1; dd[2] = d2; }
        }
    }
}

// ---------------------------------------------------------------------------
// Node kernel: layer 1 = silu(zn[node] + agg@Wn1_bot); layer 2 MFMA.
// ---------------------------------------------------------------------------
__global__ __launch_bounds__(256, 4) void egnn_node_mfma(
    const unsigned short* __restrict__ znbf, const float* __restrict__ agg,
    const float* __restrict__ delta, const float* __restrict__ pos,
    const unsigned short* __restrict__ wfn1, const unsigned short* __restrict__ wfn2,
    const float* __restrict__ bn2,
    float* __restrict__ out)
{
    __shared__ unsigned short Hs[64 * 136];

    const int tid = threadIdx.x;
    const int n0 = blockIdx.x * 64;
    const char* zn = (const char*)znbf;
    const char* ab = (const char*)agg;
    const char* w1 = (const char*)wfn1;
    const char* w2 = (const char*)wfn2;

    if (tid < 192) {
        int n = n0 + tid / 3, d = tid - 3 * (tid / 3);
        if (n < NN)
            out[(size_t)NN * 128 + (size_t)n * 3 + d] =
                pos[(size_t)n * 3 + d] + 0.01f * delta[(size_t)n * 3 + d];
    }

    const int P = tid >> 6, lane = tid & 63;
    const int q = lane >> 4, e16 = lane & 15;
    const int oc_q = P * 32 + q * 4;

    int nloc[4]; unsigned nb[4];
    #pragma unroll
    for (int t = 0; t < 4; ++t) {
        int nl = t * 16 + e16; nloc[t] = nl;
        int node = n0 + nl; if (node >= NN) node = NN - 1;
        nb[t] = (unsigned)node;
    }

    f32x4 acc[2][4];
    #pragma unroll
    for (int M = 0; M < 2; ++M) {
        const unsigned cbyte = (unsigned)((oc_q + M * 16) << 1);
        #pragma unroll
        for (int t = 0; t < 4; ++t) {
            uint2 uz = *(const uint2*)(zn + (nb[t] << 8) + cbyte);
            acc[M][t][0] = bf_lo(uz.x); acc[M][t][1] = bf_hi(uz.x);
            acc[M][t][2] = bf_lo(uz.y); acc[M][t][3] = bf_hi(uz.y);
        }
    }

    #pragma unroll
    for (int s = 0; s < 4; ++s) {
        bf8_t bfr[4];
        #pragma unroll
        for (int t = 0; t < 4; ++t) {
            unsigned aoff = (nb[t] << 9) + (unsigned)((s * 32 + q * 8) * 4);
            float4 a0 = *(const float4*)(ab + aoff);
            float4 a1 = *(const float4*)(ab + aoff + 16);
            uint4 o;
            o.x = pack2bf(a0.x, a0.y); o.y = pack2bf(a0.z, a0.w);
            o.z = pack2bf(a1.x, a1.y); o.w = pack2bf(a1.z, a1.w);
            bfr[t] = as_bf8(o);
        }
        #pragma unroll
        for (int M = 0; M < 2; ++M) {
            unsigned woff = ((unsigned)((s + 4) * 8 + P * 2 + M) << 10) + ((unsigned)lane << 4);
            bf8_t af = as_bf8(*(const uint4*)(w1 + woff));
            #pragma unroll
            for (int t = 0; t < 4; ++t)
                acc[M][t] = __builtin_amdgcn_mfma_f32_16x16x32_bf16(af, bfr[t], acc[M][t], 0, 0, 0);
        }
    }

    #pragma unroll
    for (int M = 0; M < 2; ++M) {
        #pragma unroll
        for (int t = 0; t < 4; ++t) {
            float v0 = silu_f(acc[M][t][0]);
            float v1 = silu_f(acc[M][t][1]);
            float v2 = silu_f(acc[M][t][2]);
            float v3 = silu_f(acc[M][t][3]);
            uint2 pk; pk.x = pack2bf(v0, v1); pk.y = pack2bf(v2, v3);
            *(uint2*)(Hs + nloc[t] * 136 + oc_q + M * 16) = pk;
        }
    }
    __syncthreads();

    f32x4 acc2[2][4];
    #pragma unroll
    for (int M = 0; M < 2; ++M) {
        float4 bi = *(const float4*)(bn2 + oc_q + M * 16);
        #pragma unroll
        for (int t = 0; t < 4; ++t) { acc2[M][t][0] = bi.x; acc2[M][t][1] = bi.y; acc2[M][t][2] = bi.z; acc2[M][t][3] = bi.w; }
    }

    #pragma unroll
    for (int s = 0; s < 4; ++s) {
        bf8_t bfr[4];
        #pragma unroll
        for (int t = 0; t < 4; ++t)
            bfr[t] = as_bf8(*(const uint4*)(Hs + nloc[t] * 136 + s * 32 + q * 8));
        #pragma unroll
        for (int M = 0; M < 2; ++M) {
            unsigned woff = ((unsigned)(s * 8 + P * 2 + M) << 10) + ((unsigned)lane << 4);
            bf8_t af = as_bf8(*(const uint4*)(w2 + woff));
            #pragma unroll
            for (int t = 0; t < 4; ++t)
                acc2[M][t] = __builtin_amdgcn_mfma_f32_16x16x32_bf16(af, bfr[t], acc2[M][t], 0, 0, 0);
        }
    }

    #pragma unroll
    for (int M = 0; M < 2; ++M) {
        #pragma unroll
        for (int t = 0; t < 4; ++t) {
            int node = n0 + nloc[t];
            if (node < NN) {
                float4 v; v.x = acc2[M][t][0]; v.y = acc2[M][t][1]; v.z = acc2[M][t][2]; v.w = acc2[M][t][3];
                *(float4*)(out + (size_t)node * 128 + oc_q + M * 16) = v;
            }
        }
    }
}

extern "C" void kernel_launch(void* const* d_in, const int* in_sizes, int n_in,
                              void* d_out, int out_size, void* d_ws, size_t ws_size,
                              hipStream_t stream)
{
    const float* x   = (const float*)d_in[0];
    const float* pos = (const float*)d_in[1];
    const float* We1 = (const float*)d_in[2];
    const float* be1 = (const float*)d_in[3];
    const float* We2 = (const float*)d_in[4];
    const float* be2 = (const float*)d_in[5];
    const float* Wn1 = (const float*)d_in[6];
    const float* bn1 = (const float*)d_in[7];
    const float* Wn2 = (const float*)d_in[8];
    const float* bn2 = (const float*)d_in[9];
    const float* Wc  = (const float*)d_in[10];
    const float* bc  = (const float*)d_in[11];
    const int*   ei  = (const int*)d_in[12];
    float* out = (float*)d_out;

    char* p = (char*)d_ws;
    float* agg   = (float*)p;                  p += (size_t)NN * 128 * 4;
    float* delta = (float*)p;                  p += (size_t)NN * 3 * 4;
    int* cnt     = (int*)p;                    p += (size_t)NN * 4;
    unsigned short* znbf = (unsigned short*)p; p += (size_t)NN * 128 * 2;
    unsigned short* zbf = (unsigned short*)p;  p += (size_t)NN * 128 * 2;
    unsigned short* ybf = (unsigned short*)p;  p += (size_t)NN * 128 * 2;
    unsigned short* wf1  = (unsigned short*)p; p += 65536;
    unsigned short* wf2  = (unsigned short*)p; p += 32768;
    unsigned short* wfn1 = (unsigned short*)p; p += 65536;
    unsigned short* wfn2 = (unsigned short*)p; p += 32768;
    int* off   = (int*)p;                      p += (size_t)(NN + 1) * 4 + 12;
    int* cur   = (int*)p;                      p += (size_t)NN * 4;
    int* bsum  = (int*)p;                      p += (size_t)SCAN_B * 4 + 48;  // keep rc_slot 16B-aligned
    int4* rc_slot = (int4*)p;

    hipMemsetAsync(agg, 0, ((size_t)NN * 128 + (size_t)NN * 3 + NN) * 4, stream);

    prep_w<<<192, 64, 0, stream>>>(We1, We2, Wn1, Wn2, wf1, wf2, wfn1, wfn2);
    prep_node<<<(NN + 63) / 64, 256, 0, stream>>>(x, ei, wf1, wfn1, be1, bn1,
                                                  zbf, ybf, znbf, cnt);
    scan_bsum<<<SCAN_B, 256, 0, stream>>>(cnt, bsum);
    scan_write<<<SCAN_B, 256, 0, stream>>>(cnt, bsum, off, cur);
    egnn_scatter<<<(NE / 4 + 255) / 256, 256, 0, stream>>>(ei, pos, cur, rc_slot);
    egnn_edge_mfma<<<NE / 64, 256, 0, stream>>>(zbf, ybf, pos, wf2, We1, be2,
                                                Wc, bc, rc_slot, agg, delta);
    egnn_node_mfma<<<(NN + 63) / 64, 256, 0, stream>>>(znbf, agg, delta, pos,
                                                       wfn1, wfn2, bn2, out);
}

// Round 18
// 272.402 us; speedup vs baseline: 1.0511x; 1.0511x over previous
//
#include <hip/hip_runtime.h>
#include <hip/hip_bf16.h>
#include <stdint.h>
#include <string.h>

#define NN 50000
#define NE 800000
#define SCAN_B 200
#define SCAN_CH 250

typedef short bf8_t __attribute__((ext_vector_type(8)));
typedef float f32x4 __attribute__((ext_vector_type(4)));

__device__ __forceinline__ float silu_f(float v) {
    return v * __builtin_amdgcn_rcpf(1.0f + __expf(-v));
}

__device__ __forceinline__ unsigned int pack2bf(float a, float b) {
    __hip_bfloat162 h = __float22bfloat162_rn(make_float2(a, b));
    unsigned int u; memcpy(&u, &h, 4);
    return u;
}

__device__ __forceinline__ float bf_lo(unsigned int u) { return __uint_as_float(u << 16); }
__device__ __forceinline__ float bf_hi(unsigned int u) { return __uint_as_float(u & 0xffff0000u); }

union U4B { uint4 u; bf8_t b; };
__device__ __forceinline__ bf8_t as_bf8(uint4 u) { U4B x; x.u = u; return x.b; }

// ---------------------------------------------------------------------------
// prep_w: weight fragments in MFMA A-operand order (W^T), bf16.
// ---------------------------------------------------------------------------
__global__ __launch_bounds__(64) void prep_w(const float* __restrict__ We1,
                                             const float* __restrict__ We2,
                                             const float* __restrict__ Wn1,
                                             const float* __restrict__ Wn2,
                                             unsigned short* __restrict__ wf1,
                                             unsigned short* __restrict__ wf2,
                                             unsigned short* __restrict__ wfn1,
                                             unsigned short* __restrict__ wfn2) {
    int b = blockIdx.x, lane = threadIdx.x;
    int q = lane >> 4, c = lane & 15;
    const float* W; unsigned short* dst; int f;
    if (b < 64)       { W = We1; f = b;       dst = wf1  + (size_t)f * 512; }
    else if (b < 96)  { W = We2; f = b - 64;  dst = wf2  + (size_t)f * 512; }
    else if (b < 160) { W = Wn1; f = b - 96;  dst = wfn1 + (size_t)f * 512; }
    else              { W = Wn2; f = b - 160; dst = wfn2 + (size_t)f * 512; }
    int s = f >> 3, mf = f & 7;
    int k0 = s * 32 + q * 8, col = mf * 16 + c;
    float v[8];
    #pragma unroll
    for (int i = 0; i < 8; ++i) v[i] = W[(size_t)(k0 + i) * 128 + col];
    uint4 o;
    o.x = pack2bf(v[0], v[1]); o.y = pack2bf(v[2], v[3]);
    o.z = pack2bf(v[4], v[5]); o.w = pack2bf(v[6], v[7]);
    *(uint4*)(dst + lane * 8) = o;
}

// ---------------------------------------------------------------------------
// prep_node: fused (a) edge-row histogram, (b) THREE GEMMs sharing one pass
// over x: z = x@We1_top + be1, y = x@We1_mid, zn = x@Wn1_top + bn1.
// ---------------------------------------------------------------------------
__global__ __launch_bounds__(256, 2) void prep_node(
    const float* __restrict__ x, const int* __restrict__ ei,
    const unsigned short* __restrict__ wf1, const unsigned short* __restrict__ wfn1,
    const float* __restrict__ be1, const float* __restrict__ bn1,
    unsigned short* __restrict__ zbf, unsigned short* __restrict__ ybf,
    unsigned short* __restrict__ znbf, int* __restrict__ cnt)
{
    const int tid = threadIdx.x;
    const int n0 = blockIdx.x * 64;
    const char* w1 = (const char*)wf1;
    const char* wn = (const char*)wfn1;

    {
        int e0 = (blockIdx.x * 256 + tid) * 4;
        if (e0 < NE) {
            int4 r4 = *(const int4*)(ei + e0);
            atomicAdd(&cnt[r4.x], 1); atomicAdd(&cnt[r4.y], 1);
            atomicAdd(&cnt[r4.z], 1); atomicAdd(&cnt[r4.w], 1);
        }
    }

    const int P = tid >> 6, lane = tid & 63;
    const int q = lane >> 4, e16 = lane & 15;
    const int oc_q = P * 32 + q * 4;

    int nloc[4]; unsigned nb[4];
    #pragma unroll
    for (int t = 0; t < 4; ++t) {
        int nl = t * 16 + e16; nloc[t] = nl;
        int node = n0 + nl; if (node >= NN) node = NN - 1;
        nb[t] = (unsigned)node;
    }

    f32x4 az[2][4], ay[2][4], an[2][4];
    #pragma unroll
    for (int M = 0; M < 2; ++M) {
        float4 b1 = *(const float4*)(be1 + oc_q + M * 16);
        float4 b2 = *(const float4*)(bn1 + oc_q + M * 16);
        #pragma unroll
        for (int t = 0; t < 4; ++t) {
            az[M][t][0] = b1.x; az[M][t][1] = b1.y; az[M][t][2] = b1.z; az[M][t][3] = b1.w;
            ay[M][t][0] = 0.f;  ay[M][t][1] = 0.f;  ay[M][t][2] = 0.f;  ay[M][t][3] = 0.f;
            an[M][t][0] = b2.x; an[M][t][1] = b2.y; an[M][t][2] = b2.z; an[M][t][3] = b2.w;
        }
    }

    #pragma unroll
    for (int s = 0; s < 4; ++s) {
        bf8_t bfr[4];
        #pragma unroll
        for (int t = 0; t < 4; ++t) {
            const float* src = x + ((size_t)nb[t]) * 128 + s * 32 + q * 8;
            float4 v0 = *(const float4*)src;
            float4 v1 = *(const float4*)(src + 4);
            uint4 o;
            o.x = pack2bf(v0.x, v0.y); o.y = pack2bf(v0.z, v0.w);
            o.z = pack2bf(v1.x, v1.y); o.w = pack2bf(v1.z, v1.w);
            bfr[t] = as_bf8(o);
        }
        #pragma unroll
        for (int M = 0; M < 2; ++M) {
            unsigned wz = ((unsigned)(s * 8 + P * 2 + M) << 10) + ((unsigned)lane << 4);
            unsigned wy = ((unsigned)((s + 4) * 8 + P * 2 + M) << 10) + ((unsigned)lane << 4);
            bf8_t afz = as_bf8(*(const uint4*)(w1 + wz));
            bf8_t afy = as_bf8(*(const uint4*)(w1 + wy));
            bf8_t afn = as_bf8(*(const uint4*)(wn + wz));
            #pragma unroll
            for (int t = 0; t < 4; ++t) {
                az[M][t] = __builtin_amdgcn_mfma_f32_16x16x32_bf16(afz, bfr[t], az[M][t], 0, 0, 0);
                ay[M][t] = __builtin_amdgcn_mfma_f32_16x16x32_bf16(afy, bfr[t], ay[M][t], 0, 0, 0);
                an[M][t] = __builtin_amdgcn_mfma_f32_16x16x32_bf16(afn, bfr[t], an[M][t], 0, 0, 0);
            }
        }
    }

    #pragma unroll
    for (int M = 0; M < 2; ++M) {
        #pragma unroll
        for (int t = 0; t < 4; ++t) {
            int node = n0 + nloc[t];
            if (node < NN) {
                uint2 pz, py, pn;
                pz.x = pack2bf(az[M][t][0], az[M][t][1]); pz.y = pack2bf(az[M][t][2], az[M][t][3]);
                py.x = pack2bf(ay[M][t][0], ay[M][t][1]); py.y = pack2bf(ay[M][t][2], ay[M][t][3]);
                pn.x = pack2bf(an[M][t][0], an[M][t][1]); pn.y = pack2bf(an[M][t][2], an[M][t][3]);
                *(uint2*)(zbf  + ((size_t)node << 7) + oc_q + M * 16) = pz;
                *(uint2*)(ybf  + ((size_t)node << 7) + oc_q + M * 16) = py;
                *(uint2*)(znbf + ((size_t)node << 7) + oc_q + M * 16) = pn;
            }
        }
    }
}

// ---------------------------------------------------------------------------
// Parallel CSR scan
// ---------------------------------------------------------------------------
__global__ __launch_bounds__(256) void scan_bsum(const int* __restrict__ cnt,
                                                 int* __restrict__ bsum) {
    __shared__ int red[4];
    int b = blockIdx.x, tid = threadIdx.x;
    int n = b * SCAN_CH + tid;
    int v = (tid < SCAN_CH) ? cnt[n] : 0;
    #pragma unroll
    for (int o = 32; o; o >>= 1) v += __shfl_down(v, o);
    if ((tid & 63) == 0) red[tid >> 6] = v;
    __syncthreads();
    if (tid == 0) bsum[b] = red[0] + red[1] + red[2] + red[3];
}

__global__ __launch_bounds__(256) void scan_write(const int* __restrict__ cnt,
                                                  const int* __restrict__ bsum,
                                                  int* __restrict__ off,
                                                  int* __restrict__ cur) {
    __shared__ int part[256];
    __shared__ int basered[4];
    int b = blockIdx.x, tid = threadIdx.x;
    int bv = (tid < b) ? bsum[tid] : 0;
    #pragma unroll
    for (int o = 32; o; o >>= 1) bv += __shfl_down(bv, o);
    if ((tid & 63) == 0) basered[tid >> 6] = bv;
    __syncthreads();
    int base = basered[0] + basered[1] + basered[2] + basered[3];
    int n = b * SCAN_CH + tid;
    int c = (tid < SCAN_CH) ? cnt[n] : 0;
    part[tid] = c;
    __syncthreads();
    #pragma unroll
    for (int d = 1; d < 256; d <<= 1) {
        int v = (tid >= d) ? part[tid - d] : 0;
        __syncthreads();
        part[tid] += v;
        __syncthreads();
    }
    if (tid < SCAN_CH) {
        int excl = base + part[tid] - c;
        off[n] = excl; cur[n] = excl;
    }
    if (b == SCAN_B - 1 && tid == SCAN_CH) off[NN] = NE;
}

// scatter: 4 edges/thread; computes dij and stores int4{row, col, dij, 0}
__global__ __launch_bounds__(256) void egnn_scatter(const int* __restrict__ ei,
                                                    const float* __restrict__ pos,
                                                    int* __restrict__ cur,
                                                    int4* __restrict__ rc_slot) {
    int e = (blockIdx.x * 256 + threadIdx.x) * 4;
    if (e < NE) {
        int4 r4 = *(const int4*)(ei + e);
        int4 c4 = *(const int4*)(ei + NE + e);
        #pragma unroll
        for (int j = 0; j < 4; ++j) {
            int r = (j == 0) ? r4.x : (j == 1) ? r4.y : (j == 2) ? r4.z : r4.w;
            int c = (j == 0) ? c4.x : (j == 1) ? c4.y : (j == 2) ? c4.z : c4.w;
            float dx = pos[r * 3 + 0] - pos[c * 3 + 0];
            float dy = pos[r * 3 + 1] - pos[c * 3 + 1];
            float dz = pos[r * 3 + 2] - pos[c * 3 + 2];
            float d = dx * dx + dy * dy + dz * dz;
            int p = atomicAdd(&cur[r], 1);
            rc_slot[p] = make_int4(r, c, __float_as_int(d), 0);
        }
    }
}

// ---------------------------------------------------------------------------
// Edge kernel. Block = 64 CSR slots, 256 threads = 4 waves, 3 barriers.
// (256,5) + setprio around L2 MFMA: measured-best config (R16).
// ---------------------------------------------------------------------------
__global__ __launch_bounds__(256, 5) void egnn_edge_mfma(
    const unsigned short* __restrict__ zbf, const unsigned short* __restrict__ ybf,
    const float* __restrict__ pos,
    const unsigned short* __restrict__ wf2,
    const float* __restrict__ We1,
    const float* __restrict__ be2, const float* __restrict__ Wc,
    const float* __restrict__ bc,
    const int4* __restrict__ rc_slot,
    float* __restrict__ agg, float* __restrict__ delta)
{
    __shared__ __align__(16) unsigned short HsBuf[9216];  // h1 (stride 136) / mT (stride 72)
    unsigned short* Hs = HsBuf;
    unsigned short* mT = HsBuf;
    __shared__ float rij_s[64][3];
    __shared__ float wdot[64];
    __shared__ int   seg_node[64], seg_start[65];
    __shared__ unsigned long long smask;
    __shared__ int firstPartial, lastPartial;

    const int tid = threadIdx.x;
    const int bid = blockIdx.x;
    const int xcd = bid & 7, ii = bid >> 3;
    const int blk = (xcd < 4 ? xcd * 1563 : 4 * 1563 + (xcd - 4) * 1562) + ii;
    const int e0 = blk * 64;
    const char* zb = (const char*)zbf;
    const char* yb = (const char*)ybf;
    const char* w2 = (const char*)wf2;

    const int P = tid >> 6, lane = tid & 63;
    const int q = lane >> 4, e16 = lane & 15;
    const int oc_q = P * 32 + q * 4;

    // per-thread slot records
    int eloc[4]; unsigned rb[4], cb[4]; float dijt[4];
    #pragma unroll
    for (int t = 0; t < 4; ++t) {
        int el = t * 16 + e16; eloc[t] = el;
        int4 sl = rc_slot[e0 + el];
        rb[t] = (unsigned)sl.x << 8;
        cb[t] = (unsigned)sl.y << 8;
        dijt[t] = __int_as_float(sl.z);
    }

    // hoisted z/y gathers
    uint2 uzr[2][4], uyr[2][4];
    #pragma unroll
    for (int M = 0; M < 2; ++M) {
        const unsigned cbyte = (unsigned)((oc_q + M * 16) << 1);
        #pragma unroll
        for (int t = 0; t < 4; ++t) {
            uzr[M][t] = *(const uint2*)(zb + rb[t] + cbyte);
            uyr[M][t] = *(const uint2*)(yb + cb[t] + cbyte);
        }
    }

    // wave 0: staging + segment detection, concurrent with other waves' L1
    if (tid < 64) {
        int4 sl = rc_slot[e0 + tid];
        int r = sl.x;
        #pragma unroll
        for (int k = 0; k < 3; ++k)
            rij_s[tid][k] = pos[r * 3 + k] - pos[sl.y * 3 + k];
        wdot[tid] = 0.f;
        seg_start[tid] = 64;
        if (tid == 0) seg_start[64] = 64;
        int prev = __shfl_up(r, 1);
        bool flag = (tid == 0) || (r != prev);
        unsigned long long b = __ballot(flag);
        int seg = __popcll(b & ((2ull << tid) - 1)) - 1;
        if (flag) { seg_node[seg] = r; seg_start[seg] = tid; }
        int r63 = __shfl(r, 63);
        if (tid == 0) {
            smask = b;
            firstPartial = (e0 > 0) && (rc_slot[e0 - 1].x == r);
            lastPartial  = (e0 + 64 < NE) && (rc_slot[e0 + 64].x == r63);
        }
    }

    // ---- layer 1: h1 = silu(z[row] + y[col] + dij*w256) ----
    #pragma unroll
    for (int M = 0; M < 2; ++M) {
        float4 w256 = *(const float4*)(We1 + (size_t)256 * 128 + oc_q + M * 16);
        #pragma unroll
        for (int t = 0; t < 4; ++t) {
            uint2 uz = uzr[M][t], uy = uyr[M][t];
            float d = dijt[t];
            float v0 = silu_f(bf_lo(uz.x) + bf_lo(uy.x) + d * w256.x);
            float v1 = silu_f(bf_hi(uz.x) + bf_hi(uy.x) + d * w256.y);
            float v2 = silu_f(bf_lo(uz.y) + bf_lo(uy.y) + d * w256.z);
            float v3 = silu_f(bf_hi(uz.y) + bf_hi(uy.y) + d * w256.w);
            uint2 pk; pk.x = pack2bf(v0, v1); pk.y = pack2bf(v2, v3);
            *(uint2*)(Hs + eloc[t] * 136 + oc_q + M * 16) = pk;
        }
    }
    __syncthreads();   // barrier 1

    // ---- layer 2: K=128 MFMA ----
    f32x4 acc2[2][4];
    #pragma unroll
    for (int M = 0; M < 2; ++M) {
        float4 bi = *(const float4*)(be2 + oc_q + M * 16);
        #pragma unroll
        for (int t = 0; t < 4; ++t) { acc2[M][t][0] = bi.x; acc2[M][t][1] = bi.y; acc2[M][t][2] = bi.z; acc2[M][t][3] = bi.w; }
    }

    #pragma unroll
    for (int s = 0; s < 4; ++s) {
        bf8_t bfr[4];
        #pragma unroll
        for (int t = 0; t < 4; ++t)
            bfr[t] = as_bf8(*(const uint4*)(Hs + eloc[t] * 136 + s * 32 + q * 8));
        __builtin_amdgcn_s_setprio(1);
        #pragma unroll
        for (int M = 0; M < 2; ++M) {
            unsigned woff = ((unsigned)(s * 8 + P * 2 + M) << 10) + ((unsigned)lane << 4);
            bf8_t af = as_bf8(*(const uint4*)(w2 + woff));
            #pragma unroll
            for (int t = 0; t < 4; ++t)
                acc2[M][t] = __builtin_amdgcn_mfma_f32_16x16x32_bf16(af, bfr[t], acc2[M][t], 0, 0, 0);
        }
        __builtin_amdgcn_s_setprio(0);
    }
    __syncthreads();   // barrier 2

    // ---- Phase A: m = silu(.) -> mT (transposed); wdot partials ----
    {
        float4 wcA = *(const float4*)(Wc + oc_q);
        float4 wcB = *(const float4*)(Wc + oc_q + 16);
        float part[4];
        #pragma unroll
        for (int t = 0; t < 4; ++t) part[t] = 0.f;

        #pragma unroll
        for (int M = 0; M < 2; ++M) {
            float4 wc = (M == 0) ? wcA : wcB;
            int cbase = oc_q + M * 16;
            #pragma unroll
            for (int t = 0; t < 4; ++t) {
                float v0 = silu_f(acc2[M][t][0]);
                float v1 = silu_f(acc2[M][t][1]);
                float v2 = silu_f(acc2[M][t][2]);
                float v3 = silu_f(acc2[M][t][3]);
                part[t] += v0 * wc.x + v1 * wc.y + v2 * wc.z + v3 * wc.w;
                unsigned ua = pack2bf(v0, v1), ub = pack2bf(v2, v3);
                int slot = eloc[t];
                mT[(cbase + 0) * 72 + slot] = (unsigned short)ua;
                mT[(cbase + 1) * 72 + slot] = (unsigned short)(ua >> 16);
                mT[(cbase + 2) * 72 + slot] = (unsigned short)ub;
                mT[(cbase + 3) * 72 + slot] = (unsigned short)(ub >> 16);
            }
        }
        #pragma unroll
        for (int t = 0; t < 4; ++t) {
            float p = part[t];
            p += __shfl_xor(p, 16);
            p += __shfl_xor(p, 32);
            if (q == 0) atomicAdd(&wdot[eloc[t]], p);
        }
    }
    __syncthreads();   // barrier 3

    // ---- Phase C: segment-sum ----
    {
        const int wv = tid >> 6, l = tid & 63;
        const int cA = l & 15, kq = l >> 4;
        const int nseg = __popcll(smask);

        if (nseg <= 16) {
            // fast path: selector-MFMA; wave handles 2 col-quadrants
            const int st = seg_start[cA];
            const int en = seg_start[cA + 1];
            f32x4 accd[2];
            #pragma unroll
            for (int c2 = 0; c2 < 2; ++c2) { accd[c2][0] = 0.f; accd[c2][1] = 0.f; accd[c2][2] = 0.f; accd[c2][3] = 0.f; }
            #pragma unroll
            for (int kt = 0; kt < 2; ++kt) {
                bf8_t aS;
                #pragma unroll
                for (int i = 0; i < 8; ++i) {
                    int k = kt * 32 + kq * 8 + i;
                    aS[i] = (k >= st && k < en) ? (short)0x3F80 : (short)0;
                }
                #pragma unroll
                for (int c2 = 0; c2 < 2; ++c2) {
                    int ct = wv * 2 + c2;
                    bf8_t bM = as_bf8(*(const uint4*)(mT + (ct * 16 + cA) * 72 + kt * 32 + kq * 8));
                    accd[c2] = __builtin_amdgcn_mfma_f32_16x16x32_bf16(aS, bM, accd[c2], 0, 0, 0);
                }
            }
            #pragma unroll
            for (int c2 = 0; c2 < 2; ++c2) {
                int ct = wv * 2 + c2;
                #pragma unroll
                for (int r = 0; r < 4; ++r) {
                    int sg = kq * 4 + r;
                    if (sg < nseg) {
                        float v = accd[c2][r];
                        int node = seg_node[sg];
                        bool partial = (sg == 0 && firstPartial) || (sg == nseg - 1 && lastPartial);
                        float* dst = agg + (size_t)node * 128 + ct * 16 + cA;
                        if (partial) atomicAdd(dst, v); else *dst = v;
                    }
                }
            }
        } else {
            // rare general path: SCALAR segment sums (few registers)
            const int c = tid & 127, g = tid >> 7;   // 128 cols x 2 seg groups
            for (int k = g; k < nseg; k += 2) {
                int st = seg_start[k];
                int en = seg_start[k + 1];
                float a = 0.f;
                for (int s2 = st; s2 < en; ++s2)
                    a += __uint_as_float((unsigned)mT[c * 72 + s2] << 16);
                int node = seg_node[k];
                bool partial = (k == 0 && firstPartial) || (k == nseg - 1 && lastPartial);
                float* dst = agg + (size_t)node * 128 + c;
                if (partial) atomicAdd(dst, a); else *dst = a;
            }
        }

        // delta tail
        if (tid < nseg) {
            float bcv = bc[0];
            int start = seg_start[tid];
            int end = (tid + 1 < nseg) ? seg_start[tid + 1] : 64;
            float d0 = 0.f, d1 = 0.f, d2 = 0.f;
            for (int s2 = start; s2 < end; ++s2) {
                float wgt = silu_f(wdot[s2] + bcv);
                d0 += rij_s[s2][0] * wgt;
                d1 += rij_s[s2][1] * wgt;
                d2 += rij_s[s2][2] * wgt;
            }
            int node = seg_node[tid];
            bool partial = (tid == 0 && firstPartial) || (tid == nseg - 1 && lastPartial);
            float* dd = delta + (size_t)node * 3;
            if (partial) { atomicAdd(dd, d0); atomicAdd(dd + 1, d1); atomicAdd(dd + 2, d2); }
            else         { dd[0] = d0; dd[1] = d1; dd[2] = d2; }
        }
    }
}

// ---------------------------------------------------------------------------
// Node kernel: layer 1 = silu(zn[node] + agg@Wn1_bot); layer 2 MFMA.
// ---------------------------------------------------------------------------
__global__ __launch_bounds__(256, 4) void egnn_node_mfma(
    const unsigned short* __restrict__ znbf, const float* __restrict__ agg,
    const float* __restrict__ delta, const float* __restrict__ pos,
    const unsigned short* __restrict__ wfn1, const unsigned short* __restrict__ wfn2,
    const float* __restrict__ bn2,
    float* __restrict__ out)
{
    __shared__ unsigned short Hs[64 * 136];

    const int tid = threadIdx.x;
    const int n0 = blockIdx.x * 64;
    const char* zn = (const char*)znbf;
    const char* ab = (const char*)agg;
    const char* w1 = (const char*)wfn1;
    const char* w2 = (const char*)wfn2;

    if (tid < 192) {
        int n = n0 + tid / 3, d = tid - 3 * (tid / 3);
        if (n < NN)
            out[(size_t)NN * 128 + (size_t)n * 3 + d] =
                pos[(size_t)n * 3 + d] + 0.01f * delta[(size_t)n * 3 + d];
    }

    const int P = tid >> 6, lane = tid & 63;
    const int q = lane >> 4, e16 = lane & 15;
    const int oc_q = P * 32 + q * 4;

    int nloc[4]; unsigned nb[4];
    #pragma unroll
    for (int t = 0; t < 4; ++t) {
        int nl = t * 16 + e16; nloc[t] = nl;
        int node = n0 + nl; if (node >= NN) node = NN - 1;
        nb[t] = (unsigned)node;
    }

    f32x4 acc[2][4];
    #pragma unroll
    for (int M = 0; M < 2; ++M) {
        const unsigned cbyte = (unsigned)((oc_q + M * 16) << 1);
        #pragma unroll
        for (int t = 0; t < 4; ++t) {
            uint2 uz = *(const uint2*)(zn + (nb[t] << 8) + cbyte);
            acc[M][t][0] = bf_lo(uz.x); acc[M][t][1] = bf_hi(uz.x);
            acc[M][t][2] = bf_lo(uz.y); acc[M][t][3] = bf_hi(uz.y);
        }
    }

    #pragma unroll
    for (int s = 0; s < 4; ++s) {
        bf8_t bfr[4];
        #pragma unroll
        for (int t = 0; t < 4; ++t) {
            unsigned aoff = (nb[t] << 9) + (unsigned)((s * 32 + q * 8) * 4);
            float4 a0 = *(const float4*)(ab + aoff);
            float4 a1 = *(const float4*)(ab + aoff + 16);
            uint4 o;
            o.x = pack2bf(a0.x, a0.y); o.y = pack2bf(a0.z, a0.w);
            o.z = pack2bf(a1.x, a1.y); o.w = pack2bf(a1.z, a1.w);
            bfr[t] = as_bf8(o);
        }
        #pragma unroll
        for (int M = 0; M < 2; ++M) {
            unsigned woff = ((unsigned)((s + 4) * 8 + P * 2 + M) << 10) + ((unsigned)lane << 4);
            bf8_t af = as_bf8(*(const uint4*)(w1 + woff));
            #pragma unroll
            for (int t = 0; t < 4; ++t)
                acc[M][t] = __builtin_amdgcn_mfma_f32_16x16x32_bf16(af, bfr[t], acc[M][t], 0, 0, 0);
        }
    }

    #pragma unroll
    for (int M = 0; M < 2; ++M) {
        #pragma unroll
        for (int t = 0; t < 4; ++t) {
            float v0 = silu_f(acc[M][t][0]);
            float v1 = silu_f(acc[M][t][1]);
            float v2 = silu_f(acc[M][t][2]);
            float v3 = silu_f(acc[M][t][3]);
            uint2 pk; pk.x = pack2bf(v0, v1); pk.y = pack2bf(v2, v3);
            *(uint2*)(Hs + nloc[t] * 136 + oc_q + M * 16) = pk;
        }
    }
    __syncthreads();

    f32x4 acc2[2][4];
    #pragma unroll
    for (int M = 0; M < 2; ++M) {
        float4 bi = *(const float4*)(bn2 + oc_q + M * 16);
        #pragma unroll
        for (int t = 0; t < 4; ++t) { acc2[M][t][0] = bi.x; acc2[M][t][1] = bi.y; acc2[M][t][2] = bi.z; acc2[M][t][3] = bi.w; }
    }

    #pragma unroll
    for (int s = 0; s < 4; ++s) {
        bf8_t bfr[4];
        #pragma unroll
        for (int t = 0; t < 4; ++t)
            bfr[t] = as_bf8(*(const uint4*)(Hs + nloc[t] * 136 + s * 32 + q * 8));
        #pragma unroll
        for (int M = 0; M < 2; ++M) {
            unsigned woff = ((unsigned)(s * 8 + P * 2 + M) << 10) + ((unsigned)lane << 4);
            bf8_t af = as_bf8(*(const uint4*)(w2 + woff));
            #pragma unroll
            for (int t = 0; t < 4; ++t)
                acc2[M][t] = __builtin_amdgcn_mfma_f32_16x16x32_bf16(af, bfr[t], acc2[M][t], 0, 0, 0);
        }
    }

    #pragma unroll
    for (int M = 0; M < 2; ++M) {
        #pragma unroll
        for (int t = 0; t < 4; ++t) {
            int node = n0 + nloc[t];
            if (node < NN) {
                float4 v; v.x = acc2[M][t][0]; v.y = acc2[M][t][1]; v.z = acc2[M][t][2]; v.w = acc2[M][t][3];
                *(float4*)(out + (size_t)node * 128 + oc_q + M * 16) = v;
            }
        }
    }
}

extern "C" void kernel_launch(void* const* d_in, const int* in_sizes, int n_in,
                              void* d_out, int out_size, void* d_ws, size_t ws_size,
                              hipStream_t stream)
{
    const float* x   = (const float*)d_in[0];
    const float* pos = (const float*)d_in[1];
    const float* We1 = (const float*)d_in[2];
    const float* be1 = (const float*)d_in[3];
    const float* We2 = (const float*)d_in[4];
    const float* be2 = (const float*)d_in[5];
    const float* Wn1 = (const float*)d_in[6];
    const float* bn1 = (const float*)d_in[7];
    const float* Wn2 = (const float*)d_in[8];
    const float* bn2 = (const float*)d_in[9];
    const float* Wc  = (const float*)d_in[10];
    const float* bc  = (const float*)d_in[11];
    const int*   ei  = (const int*)d_in[12];
    float* out = (float*)d_out;

    char* p = (char*)d_ws;
    float* agg   = (float*)p;                  p += (size_t)NN * 128 * 4;
    float* delta = (float*)p;                  p += (size_t)NN * 3 * 4;
    int* cnt     = (int*)p;                    p += (size_t)NN * 4;
    unsigned short* znbf = (unsigned short*)p; p += (size_t)NN * 128 * 2;
    unsigned short* zbf = (unsigned short*)p;  p += (size_t)NN * 128 * 2;
    unsigned short* ybf = (unsigned short*)p;  p += (size_t)NN * 128 * 2;
    unsigned short* wf1  = (unsigned short*)p; p += 65536;
    unsigned short* wf2  = (unsigned short*)p; p += 32768;
    unsigned short* wfn1 = (unsigned short*)p; p += 65536;
    unsigned short* wfn2 = (unsigned short*)p; p += 32768;
    int* off   = (int*)p;                      p += (size_t)(NN + 1) * 4 + 12;
    int* cur   = (int*)p;                      p += (size_t)NN * 4;
    int* bsum  = (int*)p;                      p += (size_t)SCAN_B * 4 + 48;  // keep rc_slot 16B-aligned
    int4* rc_slot = (int4*)p;

    hipMemsetAsync(agg, 0, ((size_t)NN * 128 + (size_t)NN * 3 + NN) * 4, stream);

    prep_w<<<192, 64, 0, stream>>>(We1, We2, Wn1, Wn2, wf1, wf2, wfn1, wfn2);
    prep_node<<<(NN + 63) / 64, 256, 0, stream>>>(x, ei, wf1, wfn1, be1, bn1,
                                                  zbf, ybf, znbf, cnt);
    scan_bsum<<<SCAN_B, 256, 0, stream>>>(cnt, bsum);
    scan_write<<<SCAN_B, 256, 0, stream>>>(cnt, bsum, off, cur);
    egnn_scatter<<<(NE / 4 + 255) / 256, 256, 0, stream>>>(ei, pos, cur, rc_slot);
    egnn_edge_mfma<<<NE / 64, 256, 0, stream>>>(zbf, ybf, pos, wf2, We1, be2,
                                                Wc, bc, rc_slot, agg, delta);
    egnn_node_mfma<<<(NN + 63) / 64, 256, 0, stream>>>(znbf, agg, delta, pos,
                                                       wfn1, wfn2, bn2, out);
}